// Round 5
// baseline (370.103 us; speedup 1.0000x reference)
//
#include <hip/hip_runtime.h>
#include <hip/hip_bf16.h>
#include <math.h>

typedef __hip_bfloat16 bf16;
typedef short s8v __attribute__((ext_vector_type(8)));   // 8 bf16 (4 VGPRs)
typedef float f4v __attribute__((ext_vector_type(4)));   // MFMA acc

__device__ __forceinline__ float b2f(bf16 v) { return __bfloat162float(v); }

template <bool F32>
__device__ __forceinline__ float ld(const void* p, int i) {
  if (F32) return ((const float*)p)[i];
  return b2f(((const bf16*)p)[i]);
}

__device__ __forceinline__ float sigm(float x) {
  return 0.5f * (1.0f + tanhf(0.5f * x));  // saturates cleanly, no inf
}

// Inline dtype detect: bf16 coords in [0,1) -> all halfwords have small
// exponent; f32 low halfwords are random mantissa bits -> large bf16-exponents
// appear w.p. ~0.43/halfword. Wave-uniform; call before any divergence.
__device__ __forceinline__ bool detect_f32(const void* xabs) {
  unsigned short v = ((const unsigned short*)xabs)[threadIdx.x & 63];
  int ex = (v >> 7) & 0xFF;
  return __ballot(ex >= 0x93) != 0ull;
}

// ---------------------------------------------------------------------------
// K1: Z[m, g*64+e] = sum_d h0[m,d] * Wsoc[e, g*128+d], stored bf16.
// bf16 path: MFMA 16x16x32, grid 1024 x 256thr (passed R4, unchanged).
// ---------------------------------------------------------------------------
__device__ void zgemm_f32_body(const void* h0, const void* Wsoc,
                               bf16* __restrict__ Z) {
  const int mt = blockIdx.x & 15;
  const int g  = blockIdx.x >> 4;
  __shared__ __align__(16) float Asm[64][68];
  __shared__ __align__(16) float Bsm[64][68];
  const int tid = threadIdx.x;
  const int tm = tid & 15, te = tid >> 4;
  float acc[4][4] = {};
  for (int dc = 0; dc < 128; dc += 64) {
    for (int idx = tid; idx < 64 * 64; idx += 256) {
      int r = idx >> 6, d = idx & 63;
      Asm[d][r] = ld<true>(h0, (mt * 64 + r) * 128 + dc + d);
      Bsm[d][r] = ld<true>(Wsoc, r * 8192 + g * 128 + dc + d);
    }
    __syncthreads();
    for (int d = 0; d < 64; ++d) {
      float4 a = *reinterpret_cast<const float4*>(&Asm[d][tm * 4]);
      float4 b = *reinterpret_cast<const float4*>(&Bsm[d][te * 4]);
      float av[4] = {a.x, a.y, a.z, a.w};
      float bv[4] = {b.x, b.y, b.z, b.w};
#pragma unroll
      for (int i = 0; i < 4; ++i)
#pragma unroll
        for (int j = 0; j < 4; ++j) acc[i][j] += av[i] * bv[j];
    }
    __syncthreads();
  }
  const int m0 = mt * 64 + tm * 4, e0 = g * 64 + te * 4;
#pragma unroll
  for (int i = 0; i < 4; ++i) {
    bf16 tmp[4];
#pragma unroll
    for (int j = 0; j < 4; ++j) tmp[j] = __float2bfloat16(acc[i][j]);
    *reinterpret_cast<uint2*>(&Z[(size_t)(m0 + i) * 4096 + e0]) =
        *reinterpret_cast<uint2*>(tmp);
  }
}

__global__ __launch_bounds__(256) void k_zgemm(const void* h0v, const void* Wsocv,
                                               bf16* __restrict__ Z,
                                               const void* xabs) {
  if (detect_f32(xabs)) {
    if (blockIdx.x < 1024) zgemm_f32_body(h0v, Wsocv, Z);
    return;
  }
  const bf16* h0 = (const bf16*)h0v;
  const bf16* Wsoc = (const bf16*)Wsocv;
  const int wave = threadIdx.x >> 6, lane = threadIdx.x & 63;
  const int mt = blockIdx.x & 63;
  const int g  = (blockIdx.x >> 6) * 4 + wave;
  const int r16 = lane & 15, quad = lane >> 4;
  s8v afr[4];
#pragma unroll
  for (int kq = 0; kq < 4; ++kq)
    afr[kq] = *reinterpret_cast<const s8v*>(
        &h0[(mt * 16 + r16) * 128 + kq * 32 + quad * 8]);
  f4v acc[4] = {{0.f, 0.f, 0.f, 0.f}, {0.f, 0.f, 0.f, 0.f},
                {0.f, 0.f, 0.f, 0.f}, {0.f, 0.f, 0.f, 0.f}};
#pragma unroll
  for (int t = 0; t < 4; ++t) {
#pragma unroll
    for (int kq = 0; kq < 4; ++kq) {
      s8v bfr = *reinterpret_cast<const s8v*>(
          &Wsoc[(size_t)(t * 16 + r16) * 8192 + g * 128 + kq * 32 + quad * 8]);
      acc[t] = __builtin_amdgcn_mfma_f32_16x16x32_bf16(afr[kq], bfr, acc[t],
                                                       0, 0, 0);
    }
  }
#pragma unroll
  for (int t = 0; t < 4; ++t)
#pragma unroll
    for (int reg = 0; reg < 4; ++reg)
      Z[(size_t)(mt * 16 + quad * 4 + reg) * 4096 + g * 64 + t * 16 + r16] =
          __float2bfloat16(acc[t][reg]);
}

// ---------------------------------------------------------------------------
// K2 (fused): per block of 4 n's: gather -> gates MFMA -> LSTM -> out MFMA.
// LDS: [0,32K) G f32[16][512]  (aliases lists int[4][1024] in gather phase)
//      [32K,40K) Xb bf16[16][256]   [40K,44K) Hb bf16[16][128]
// ---------------------------------------------------------------------------
__device__ void fused_f32_body(const void* xabs, const void* h0,
                               const void* Wemb, const void* bemb,
                               const void* bsoc, const void* Wih,
                               const void* Whh, const void* bih,
                               const void* bhh, const void* c0,
                               const void* Wout, const void* bout,
                               const bf16* __restrict__ Z, void* out,
                               char* smem) {
  int* lists = (int*)smem;              // [4][1024]
  float* Xf  = (float*)(smem + 32768);  // [4][256]
  float* Gf  = (float*)smem;            // [4][512] (after gather)
  float* Hf  = (float*)(smem + 40960);  // [4][128]
  const int tid = threadIdx.x;
  const int wave = tid >> 6, lane = tid & 63;
  const int n = blockIdx.x * 4 + wave;

  const float xn = ld<true>(xabs, 2 * n);
  const float yn = ld<true>(xabs, 2 * n + 1);
  const float tx = xn - 0.2f, ty = yn - 0.2f;
  int* mylist = lists + wave * 1024;
  int cnt = 0;
  for (int c = 0; c < 16; ++c) {
    const int m = c * 64 + lane;
    float dx = ld<true>(xabs, 2 * m) - tx;
    float dy = ld<true>(xabs, 2 * m + 1) - ty;
    int cx = (int)floorf(dx / 0.4f * 8.0f);
    int cy = (int)floorf(dy / 0.4f * 8.0f);
    bool valid = (dx >= 0.f) & (dx < 0.4f) & (dy >= 0.f) & (dy < 0.4f) &
                 (cx >= 0) & (cx < 8) & (cy >= 0) & (cy < 8) & (m != n);
    unsigned long long msk = __ballot(valid);
    if (valid) {
      int pos = cnt + __popcll(msk & ((1ull << lane) - 1ull));
      mylist[pos] = (m << 6) | (cx + cy * 8);
    }
    cnt += __popcll(msk);
  }
  float a0 = 0.f, a1 = 0.f;
  int i = 0;
  for (; i + 2 <= cnt; i += 2) {
    int e0 = mylist[i], e1 = mylist[i + 1];
    a0 += b2f(Z[(size_t)(e0 >> 6) * 4096 + (e0 & 63) * 64 + lane]);
    a1 += b2f(Z[(size_t)(e1 >> 6) * 4096 + (e1 & 63) * 64 + lane]);
  }
  if (i < cnt) {
    int e0 = mylist[i];
    a0 += b2f(Z[(size_t)(e0 >> 6) * 4096 + (e0 & 63) * 64 + lane]);
  }
  float pool = fmaxf(a0 + a1 + ld<true>(bsoc, lane), 0.f);
  float emb = fmaxf(ld<true>(Wemb, lane * 2) * xn +
                        ld<true>(Wemb, lane * 2 + 1) * yn + ld<true>(bemb, lane),
                    0.f);
  Xf[wave * 256 + lane] = emb;
  Xf[wave * 256 + 64 + lane] = pool;
  Xf[wave * 256 + 128 + lane] = ld<true>(h0, n * 128 + lane);
  Xf[wave * 256 + 192 + lane] = ld<true>(h0, n * 128 + 64 + lane);
  __syncthreads();

  // gates: each thread -> row m=wave, 8 j's (lane + 64*jj)
  float acc8[8] = {};
  for (int k = 0; k < 256; ++k) {
    float x = Xf[wave * 256 + k];
#pragma unroll
    for (int jj = 0; jj < 8; ++jj) {
      int j = lane + jj * 64;
      float w = (k < 128) ? ld<true>(Wih, j * 128 + k)
                          : ld<true>(Whh, j * 128 + k - 128);
      acc8[jj] += x * w;
    }
  }
#pragma unroll
  for (int jj = 0; jj < 8; ++jj) {
    int j = lane + jj * 64;
    Gf[wave * 512 + j] = acc8[jj] + ld<true>(bih, j) + ld<true>(bhh, j);
  }
  __syncthreads();
  for (int idx = tid; idx < 512; idx += 256) {
    int m = idx >> 7, tt = idx & 127;
    float ig = Gf[m * 512 + tt], fg = Gf[m * 512 + 128 + tt];
    float gg = Gf[m * 512 + 256 + tt], og = Gf[m * 512 + 384 + tt];
    float c = sigm(fg) * ld<true>(c0, (blockIdx.x * 4 + m) * 128 + tt) +
              sigm(ig) * tanhf(gg);
    Hf[m * 128 + tt] = sigm(og) * tanhf(c);
  }
  __syncthreads();
#pragma unroll
  for (int jj = 0; jj < 2; ++jj) {
    int j = lane + jj * 64;
    if (j < 120) {
      float a = 0.f;
      for (int k = 0; k < 128; ++k)
        a += Hf[wave * 128 + k] * ld<true>(Wout, j * 128 + k);
      a += ld<true>(bout, j);
      ((float*)out)[(j / 20) * 20480 + n * 20 + (j % 20)] = a;
    }
  }
}

__global__ __launch_bounds__(256) void k_fused(
    const void* xabs, const void* h0, const void* Wemb, const void* bemb,
    const void* bsoc, const void* Wih, const void* Whh, const void* bih,
    const void* bhh, const void* c0, const void* Wout, const void* bout,
    const bf16* __restrict__ Z, void* out) {
  __shared__ __align__(16) char smem[45056];
  if (detect_f32(xabs)) {
    fused_f32_body(xabs, h0, Wemb, bemb, bsoc, Wih, Whh, bih, bhh, c0, Wout,
                   bout, Z, out, smem);
    return;
  }
  float* G   = (float*)smem;             // [16][512]
  int* lists = (int*)smem;               // [4][1024] (gather phase only)
  bf16* Xb   = (bf16*)(smem + 32768);    // [16][256]
  bf16* Hb   = (bf16*)(smem + 40960);    // [16][128]
  const int tid = threadIdx.x;
  const int wave = tid >> 6, lane = tid & 63;
  const int r16 = lane & 15, quad = lane >> 4;
  const bf16* xab = (const bf16*)xabs;
  const bf16* h0b = (const bf16*)h0;

  // zero MFMA pad rows 4..15 (never written elsewhere)
  for (int idx = 1024 + tid; idx < 4096; idx += 256)
    Xb[idx] = __float2bfloat16(0.f);
  for (int idx = 512 + tid; idx < 2048; idx += 256)
    Hb[idx] = __float2bfloat16(0.f);

  // ---- gather: wave-private list + ILP-8 drain ----
  const int n = blockIdx.x * 4 + wave;
  const float xn = b2f(xab[2 * n]);
  const float yn = b2f(xab[2 * n + 1]);
  const float tx = xn - 0.2f, ty = yn - 0.2f;
  int* mylist = lists + wave * 1024;
  int cnt = 0;
  for (int c = 0; c < 16; ++c) {
    const int m = c * 64 + lane;
    float dx = b2f(xab[2 * m]) - tx;
    float dy = b2f(xab[2 * m + 1]) - ty;
    int cx = (int)floorf(dx / 0.4f * 8.0f);
    int cy = (int)floorf(dy / 0.4f * 8.0f);
    bool valid = (dx >= 0.f) & (dx < 0.4f) & (dy >= 0.f) & (dy < 0.4f) &
                 (cx >= 0) & (cx < 8) & (cy >= 0) & (cy < 8) & (m != n);
    unsigned long long msk = __ballot(valid);
    if (valid) {
      int pos = cnt + __popcll(msk & ((1ull << lane) - 1ull));
      mylist[pos] = (m << 6) | (cx + cy * 8);
    }
    cnt += __popcll(msk);
  }
  float a0 = 0.f, a1 = 0.f, a2 = 0.f, a3 = 0.f;
  float a4 = 0.f, a5 = 0.f, a6 = 0.f, a7 = 0.f;
  int i = 0;
  for (; i + 8 <= cnt; i += 8) {
    int e0 = mylist[i],     e1 = mylist[i + 1];
    int e2 = mylist[i + 2], e3 = mylist[i + 3];
    int e4 = mylist[i + 4], e5 = mylist[i + 5];
    int e6 = mylist[i + 6], e7 = mylist[i + 7];
    a0 += b2f(Z[(size_t)(e0 >> 6) * 4096 + (e0 & 63) * 64 + lane]);
    a1 += b2f(Z[(size_t)(e1 >> 6) * 4096 + (e1 & 63) * 64 + lane]);
    a2 += b2f(Z[(size_t)(e2 >> 6) * 4096 + (e2 & 63) * 64 + lane]);
    a3 += b2f(Z[(size_t)(e3 >> 6) * 4096 + (e3 & 63) * 64 + lane]);
    a4 += b2f(Z[(size_t)(e4 >> 6) * 4096 + (e4 & 63) * 64 + lane]);
    a5 += b2f(Z[(size_t)(e5 >> 6) * 4096 + (e5 & 63) * 64 + lane]);
    a6 += b2f(Z[(size_t)(e6 >> 6) * 4096 + (e6 & 63) * 64 + lane]);
    a7 += b2f(Z[(size_t)(e7 >> 6) * 4096 + (e7 & 63) * 64 + lane]);
  }
  for (; i < cnt; ++i) {
    int e0 = mylist[i];
    a0 += b2f(Z[(size_t)(e0 >> 6) * 4096 + (e0 & 63) * 64 + lane]);
  }
  float pool = ((a0 + a1) + (a2 + a3)) + ((a4 + a5) + (a6 + a7));
  pool = fmaxf(pool + b2f(((const bf16*)bsoc)[lane]), 0.f);
  float emb = fmaxf(b2f(((const bf16*)Wemb)[lane * 2]) * xn +
                        b2f(((const bf16*)Wemb)[lane * 2 + 1]) * yn +
                        b2f(((const bf16*)bemb)[lane]),
                    0.f);
  Xb[wave * 256 + lane] = __float2bfloat16(emb);
  Xb[wave * 256 + 64 + lane] = __float2bfloat16(pool);
  Xb[wave * 256 + 128 + lane] = h0b[n * 128 + lane];
  Xb[wave * 256 + 192 + lane] = h0b[n * 128 + 64 + lane];
  __syncthreads();  // lists dead; G region live from here

  // ---- gates MFMA: A = Xb rows (m = n-local), B = Wih/Whh rows j ----
  const bf16* WihB = (const bf16*)Wih;
  const bf16* WhhB = (const bf16*)Whh;
  s8v afr[8];
#pragma unroll
  for (int kq = 0; kq < 8; ++kq)
    afr[kq] = *reinterpret_cast<const s8v*>(&Xb[r16 * 256 + kq * 32 + quad * 8]);
  const int j0w = wave * 128;
  f4v bacc[8];
#pragma unroll
  for (int jt = 0; jt < 8; ++jt) bacc[jt] = (f4v){0.f, 0.f, 0.f, 0.f};
#pragma unroll
  for (int jt = 0; jt < 8; ++jt) {
    int j = j0w + jt * 16 + r16;
#pragma unroll
    for (int kq = 0; kq < 4; ++kq) {
      s8v bfr = *reinterpret_cast<const s8v*>(&WihB[j * 128 + kq * 32 + quad * 8]);
      bacc[jt] = __builtin_amdgcn_mfma_f32_16x16x32_bf16(afr[kq], bfr, bacc[jt],
                                                         0, 0, 0);
    }
#pragma unroll
    for (int kq = 0; kq < 4; ++kq) {
      s8v bfr = *reinterpret_cast<const s8v*>(&WhhB[j * 128 + kq * 32 + quad * 8]);
      bacc[jt] = __builtin_amdgcn_mfma_f32_16x16x32_bf16(afr[kq + 4], bfr,
                                                         bacc[jt], 0, 0, 0);
    }
  }
#pragma unroll
  for (int jt = 0; jt < 8; ++jt) {
    int j = j0w + jt * 16 + r16;
    float bias = b2f(((const bf16*)bih)[j]) + b2f(((const bf16*)bhh)[j]);
#pragma unroll
    for (int reg = 0; reg < 4; ++reg)
      G[(quad * 4 + reg) * 512 + j] = bacc[jt][reg] + bias;
  }
  __syncthreads();

  // ---- LSTM elementwise (valid rows 0..3) ----
  const bf16* c0b = (const bf16*)c0;
  for (int idx = tid; idx < 512; idx += 256) {
    int m = idx >> 7, tt = idx & 127;
    float ig = G[m * 512 + tt], fg = G[m * 512 + 128 + tt];
    float gg = G[m * 512 + 256 + tt], og = G[m * 512 + 384 + tt];
    float c = sigm(fg) * b2f(c0b[(blockIdx.x * 4 + m) * 128 + tt]) +
              sigm(ig) * tanhf(gg);
    Hb[m * 128 + tt] = __float2bfloat16(sigm(og) * tanhf(c));
  }
  __syncthreads();

  // ---- out MFMA: A = Hb rows, B = Wout rows (clamped), j<120 masked ----
  const bf16* WoutB = (const bf16*)Wout;
  s8v hfr[4];
#pragma unroll
  for (int kq = 0; kq < 4; ++kq)
    hfr[kq] = *reinterpret_cast<const s8v*>(&Hb[r16 * 128 + kq * 32 + quad * 8]);
#pragma unroll
  for (int jt2 = 0; jt2 < 2; ++jt2) {
    int j = wave * 32 + jt2 * 16 + r16;
    int jj = j < 120 ? j : 119;
    f4v oacc = (f4v){0.f, 0.f, 0.f, 0.f};
#pragma unroll
    for (int kq = 0; kq < 4; ++kq) {
      s8v bfr =
          *reinterpret_cast<const s8v*>(&WoutB[jj * 128 + kq * 32 + quad * 8]);
      oacc = __builtin_amdgcn_mfma_f32_16x16x32_bf16(hfr[kq], bfr, oacc, 0, 0, 0);
    }
    if (j < 120 && quad == 0) {
      float bo = b2f(((const bf16*)bout)[j]);
      int kk = j / 20, mm = j % 20;
#pragma unroll
      for (int reg = 0; reg < 4; ++reg)
        ((bf16*)out)[kk * 20480 + (blockIdx.x * 4 + reg) * 20 + mm] =
            __float2bfloat16(oacc[reg] + bo);
    }
  }
}

// ---------------------------------------------------------------------------
extern "C" void kernel_launch(void* const* d_in, const int* in_sizes, int n_in,
                              void* d_out, int out_size, void* d_ws, size_t ws_size,
                              hipStream_t stream) {
  const void* xabs = d_in[0];
  const void* h0   = d_in[1];
  const void* c0   = d_in[2];
  const void* Wemb = d_in[3];
  const void* bemb = d_in[4];
  const void* Wsoc = d_in[5];
  const void* bsoc = d_in[6];
  const void* Wih  = d_in[7];
  const void* Whh  = d_in[8];
  const void* bih  = d_in[9];
  const void* bhh  = d_in[10];
  const void* Wout = d_in[11];
  const void* bout = d_in[12];

  bf16* Z = (bf16*)d_ws;  // [1024 x 4096] bf16, 8 MB

  k_zgemm<<<dim3(1024), dim3(256), 0, stream>>>(h0, Wsoc, Z, xabs);
  k_fused<<<dim3(256), dim3(256), 0, stream>>>(xabs, h0, Wemb, bemb, bsoc, Wih,
                                               Whh, bih, bhh, c0, Wout, bout, Z,
                                               d_out);
}

// Round 6
// 144.187 us; speedup vs baseline: 2.5668x; 2.5668x over previous
//
#include <hip/hip_runtime.h>
#include <hip/hip_bf16.h>
#include <math.h>

typedef __hip_bfloat16 bf16;
typedef short s8v __attribute__((ext_vector_type(8)));   // 8 bf16 (4 VGPRs)
typedef float f4v __attribute__((ext_vector_type(4)));   // MFMA acc

__device__ __forceinline__ float b2f(bf16 v) { return __bfloat162float(v); }
__device__ __forceinline__ short f2bs(float x) {
  bf16 t = __float2bfloat16(x);
  return *reinterpret_cast<short*>(&t);
}

template <bool F32>
__device__ __forceinline__ float ld(const void* p, int i) {
  if (F32) return ((const float*)p)[i];
  return b2f(((const bf16*)p)[i]);
}

// 8 consecutive elements at elem-index i, returned as a bf16x8 MFMA fragment.
// F32: two float4 loads + in-register cvt. bf16: one 16B load.
template <bool F32>
__device__ __forceinline__ s8v ldfrag(const void* p, size_t i) {
  if (F32) {
    const float* f = (const float*)p + i;
    float4 u = *reinterpret_cast<const float4*>(f);
    float4 v = *reinterpret_cast<const float4*>(f + 4);
    s8v r;
    r[0] = f2bs(u.x); r[1] = f2bs(u.y); r[2] = f2bs(u.z); r[3] = f2bs(u.w);
    r[4] = f2bs(v.x); r[5] = f2bs(v.y); r[6] = f2bs(v.z); r[7] = f2bs(v.w);
    return r;
  }
  return *reinterpret_cast<const s8v*>((const bf16*)p + i);
}

__device__ __forceinline__ float sigm(float x) {
  return 0.5f * (1.0f + tanhf(0.5f * x));
}

// Wave-uniform dtype detect (validated R2-R5: chose correctly each round).
__device__ __forceinline__ bool detect_f32(const void* xabs) {
  unsigned short v = ((const unsigned short*)xabs)[threadIdx.x & 63];
  int ex = (v >> 7) & 0xFF;
  return __ballot(ex >= 0x93) != 0ull;
}

// ---------------------------------------------------------------------------
// K1: Z[m, g*64+e] = sum_d h0[m,d]*Wsoc[e, g*128+d] (bf16 out). MFMA 16x16x32.
// grid 1024: mt = b&63 (16 m-rows each), wave w -> g = (b>>6)*4 + w.
// ---------------------------------------------------------------------------
template <bool F32>
__device__ __forceinline__ void zgemm_body(const void* h0, const void* Wsoc,
                                           bf16* __restrict__ Z) {
  const int wave = threadIdx.x >> 6, lane = threadIdx.x & 63;
  const int mt = blockIdx.x & 63;
  const int g  = (blockIdx.x >> 6) * 4 + wave;
  const int r16 = lane & 15, quad = lane >> 4;
  s8v afr[4];
#pragma unroll
  for (int kq = 0; kq < 4; ++kq)
    afr[kq] = ldfrag<F32>(h0, (size_t)(mt * 16 + r16) * 128 + kq * 32 + quad * 8);
  f4v acc[4] = {{0.f, 0.f, 0.f, 0.f}, {0.f, 0.f, 0.f, 0.f},
                {0.f, 0.f, 0.f, 0.f}, {0.f, 0.f, 0.f, 0.f}};
#pragma unroll
  for (int t = 0; t < 4; ++t) {
#pragma unroll
    for (int kq = 0; kq < 4; ++kq) {
      s8v bfr = ldfrag<F32>(
          Wsoc, (size_t)(t * 16 + r16) * 8192 + g * 128 + kq * 32 + quad * 8);
      acc[t] = __builtin_amdgcn_mfma_f32_16x16x32_bf16(afr[kq], bfr, acc[t],
                                                       0, 0, 0);
    }
  }
#pragma unroll
  for (int t = 0; t < 4; ++t)
#pragma unroll
    for (int reg = 0; reg < 4; ++reg)
      Z[(size_t)(mt * 16 + quad * 4 + reg) * 4096 + g * 64 + t * 16 + r16] =
          __float2bfloat16(acc[t][reg]);
}

__global__ __launch_bounds__(256) void k_zgemm(const void* h0, const void* Wsoc,
                                               bf16* __restrict__ Z,
                                               const void* xabs) {
  if (detect_f32(xabs)) zgemm_body<true>(h0, Wsoc, Z);
  else                  zgemm_body<false>(h0, Wsoc, Z);
}

// ---------------------------------------------------------------------------
// K2 (fused): block = 4 n's. gather (wave-private list, ILP-8 drain) ->
// gates MFMA -> LSTM elementwise -> out MFMA.
// LDS: [0,32K) G f32[16][512] (aliases lists int[4][1024] in gather phase)
//      [32K,40K) Xb bf16[16][256]   [40K,44K) Hb bf16[16][128]
// ---------------------------------------------------------------------------
template <bool F32>
__device__ __forceinline__ void fused_body(
    const void* xabs, const void* h0, const void* Wemb, const void* bemb,
    const void* bsoc, const void* Wih, const void* Whh, const void* bih,
    const void* bhh, const void* c0, const void* Wout, const void* bout,
    const bf16* __restrict__ Z, void* out, char* smem) {
  float* G   = (float*)smem;           // [16][512]
  int* lists = (int*)smem;             // [4][1024] (gather phase only)
  bf16* Xb   = (bf16*)(smem + 32768);  // [16][256]
  bf16* Hb   = (bf16*)(smem + 40960);  // [16][128]
  const int tid = threadIdx.x;
  const int wave = tid >> 6, lane = tid & 63;
  const int r16 = lane & 15, quad = lane >> 4;

  // zero MFMA pad rows 4..15
  for (int idx = 1024 + tid; idx < 4096; idx += 256)
    Xb[idx] = __float2bfloat16(0.f);
  for (int idx = 512 + tid; idx < 2048; idx += 256)
    Hb[idx] = __float2bfloat16(0.f);

  // ---- gather ----
  const int n = blockIdx.x * 4 + wave;
  const float xn = ld<F32>(xabs, 2 * n);
  const float yn = ld<F32>(xabs, 2 * n + 1);
  const float tx = xn - 0.2f, ty = yn - 0.2f;
  int* mylist = lists + wave * 1024;
  int cnt = 0;
  for (int c = 0; c < 16; ++c) {
    const int m = c * 64 + lane;
    float dx = ld<F32>(xabs, 2 * m) - tx;
    float dy = ld<F32>(xabs, 2 * m + 1) - ty;
    int cx = (int)floorf(dx / 0.4f * 8.0f);
    int cy = (int)floorf(dy / 0.4f * 8.0f);
    bool valid = (dx >= 0.f) & (dx < 0.4f) & (dy >= 0.f) & (dy < 0.4f) &
                 (cx >= 0) & (cx < 8) & (cy >= 0) & (cy < 8) & (m != n);
    unsigned long long msk = __ballot(valid);
    if (valid) {
      int pos = cnt + __popcll(msk & ((1ull << lane) - 1ull));
      mylist[pos] = (m << 6) | (cx + cy * 8);
    }
    cnt += __popcll(msk);
  }
  float a0 = 0.f, a1 = 0.f, a2 = 0.f, a3 = 0.f;
  float a4 = 0.f, a5 = 0.f, a6 = 0.f, a7 = 0.f;
  int i = 0;
  for (; i + 8 <= cnt; i += 8) {
    int e0 = mylist[i],     e1 = mylist[i + 1];
    int e2 = mylist[i + 2], e3 = mylist[i + 3];
    int e4 = mylist[i + 4], e5 = mylist[i + 5];
    int e6 = mylist[i + 6], e7 = mylist[i + 7];
    a0 += b2f(Z[(size_t)(e0 >> 6) * 4096 + (e0 & 63) * 64 + lane]);
    a1 += b2f(Z[(size_t)(e1 >> 6) * 4096 + (e1 & 63) * 64 + lane]);
    a2 += b2f(Z[(size_t)(e2 >> 6) * 4096 + (e2 & 63) * 64 + lane]);
    a3 += b2f(Z[(size_t)(e3 >> 6) * 4096 + (e3 & 63) * 64 + lane]);
    a4 += b2f(Z[(size_t)(e4 >> 6) * 4096 + (e4 & 63) * 64 + lane]);
    a5 += b2f(Z[(size_t)(e5 >> 6) * 4096 + (e5 & 63) * 64 + lane]);
    a6 += b2f(Z[(size_t)(e6 >> 6) * 4096 + (e6 & 63) * 64 + lane]);
    a7 += b2f(Z[(size_t)(e7 >> 6) * 4096 + (e7 & 63) * 64 + lane]);
  }
  for (; i < cnt; ++i) {
    int e0 = mylist[i];
    a0 += b2f(Z[(size_t)(e0 >> 6) * 4096 + (e0 & 63) * 64 + lane]);
  }
  float pool = ((a0 + a1) + (a2 + a3)) + ((a4 + a5) + (a6 + a7));
  pool = fmaxf(pool + ld<F32>(bsoc, lane), 0.f);
  float emb = fmaxf(ld<F32>(Wemb, lane * 2) * xn +
                        ld<F32>(Wemb, lane * 2 + 1) * yn + ld<F32>(bemb, lane),
                    0.f);
  Xb[wave * 256 + lane] = __float2bfloat16(emb);
  Xb[wave * 256 + 64 + lane] = __float2bfloat16(pool);
  Xb[wave * 256 + 128 + lane] = __float2bfloat16(ld<F32>(h0, n * 128 + lane));
  Xb[wave * 256 + 192 + lane] =
      __float2bfloat16(ld<F32>(h0, n * 128 + 64 + lane));
  __syncthreads();  // lists dead; G live from here

  // ---- gates MFMA: G[m, j] = X[m,:] . W_cat[j,:], j = wave*128 + jt*16+r16
  s8v afr[8];
#pragma unroll
  for (int kq = 0; kq < 8; ++kq)
    afr[kq] = *reinterpret_cast<const s8v*>(&Xb[r16 * 256 + kq * 32 + quad * 8]);
  const int j0w = wave * 128;
  f4v bacc[8];
#pragma unroll
  for (int jt = 0; jt < 8; ++jt) bacc[jt] = (f4v){0.f, 0.f, 0.f, 0.f};
#pragma unroll
  for (int jt = 0; jt < 8; ++jt) {
    int j = j0w + jt * 16 + r16;
#pragma unroll
    for (int kq = 0; kq < 4; ++kq) {
      s8v bfr = ldfrag<F32>(Wih, (size_t)j * 128 + kq * 32 + quad * 8);
      bacc[jt] = __builtin_amdgcn_mfma_f32_16x16x32_bf16(afr[kq], bfr, bacc[jt],
                                                         0, 0, 0);
    }
#pragma unroll
    for (int kq = 0; kq < 4; ++kq) {
      s8v bfr = ldfrag<F32>(Whh, (size_t)j * 128 + kq * 32 + quad * 8);
      bacc[jt] = __builtin_amdgcn_mfma_f32_16x16x32_bf16(afr[kq + 4], bfr,
                                                         bacc[jt], 0, 0, 0);
    }
  }
#pragma unroll
  for (int jt = 0; jt < 8; ++jt) {
    int j = j0w + jt * 16 + r16;
    float bias = ld<F32>(bih, j) + ld<F32>(bhh, j);
#pragma unroll
    for (int reg = 0; reg < 4; ++reg)
      G[(quad * 4 + reg) * 512 + j] = bacc[jt][reg] + bias;
  }
  __syncthreads();

  // ---- LSTM elementwise (rows 0..3 valid) ----
  for (int idx = tid; idx < 512; idx += 256) {
    int m = idx >> 7, tt = idx & 127;
    float ig = G[m * 512 + tt], fg = G[m * 512 + 128 + tt];
    float gg = G[m * 512 + 256 + tt], og = G[m * 512 + 384 + tt];
    float c = sigm(fg) * ld<F32>(c0, (blockIdx.x * 4 + m) * 128 + tt) +
              sigm(ig) * tanhf(gg);
    Hb[m * 128 + tt] = __float2bfloat16(sigm(og) * tanhf(c));
  }
  __syncthreads();

  // ---- out MFMA: O[m, j] = H[m,:] . Wout[j,:], j < 120 ----
  s8v hfr[4];
#pragma unroll
  for (int kq = 0; kq < 4; ++kq)
    hfr[kq] = *reinterpret_cast<const s8v*>(&Hb[r16 * 128 + kq * 32 + quad * 8]);
#pragma unroll
  for (int jt2 = 0; jt2 < 2; ++jt2) {
    int j = wave * 32 + jt2 * 16 + r16;
    int jj = j < 120 ? j : 119;
    f4v oacc = (f4v){0.f, 0.f, 0.f, 0.f};
#pragma unroll
    for (int kq = 0; kq < 4; ++kq) {
      s8v bfr = ldfrag<F32>(Wout, (size_t)jj * 128 + kq * 32 + quad * 8);
      oacc = __builtin_amdgcn_mfma_f32_16x16x32_bf16(hfr[kq], bfr, oacc, 0, 0, 0);
    }
    if (j < 120 && quad == 0) {
      float bo = ld<F32>(bout, j);
      int kk = j / 20, mm = j % 20;
#pragma unroll
      for (int reg = 0; reg < 4; ++reg) {
        int oi = kk * 20480 + (blockIdx.x * 4 + reg) * 20 + mm;
        float val = oacc[reg] + bo;
        if (F32) ((float*)out)[oi] = val;
        else     ((bf16*)out)[oi] = __float2bfloat16(val);
      }
    }
  }
}

__global__ __launch_bounds__(256) void k_fused(
    const void* xabs, const void* h0, const void* Wemb, const void* bemb,
    const void* bsoc, const void* Wih, const void* Whh, const void* bih,
    const void* bhh, const void* c0, const void* Wout, const void* bout,
    const bf16* __restrict__ Z, void* out) {
  __shared__ __align__(16) char smem[45056];
  if (detect_f32(xabs))
    fused_body<true>(xabs, h0, Wemb, bemb, bsoc, Wih, Whh, bih, bhh, c0, Wout,
                     bout, Z, out, smem);
  else
    fused_body<false>(xabs, h0, Wemb, bemb, bsoc, Wih, Whh, bih, bhh, c0, Wout,
                      bout, Z, out, smem);
}

// ---------------------------------------------------------------------------
extern "C" void kernel_launch(void* const* d_in, const int* in_sizes, int n_in,
                              void* d_out, int out_size, void* d_ws, size_t ws_size,
                              hipStream_t stream) {
  const void* xabs = d_in[0];
  const void* h0   = d_in[1];
  const void* c0   = d_in[2];
  const void* Wemb = d_in[3];
  const void* bemb = d_in[4];
  const void* Wsoc = d_in[5];
  const void* bsoc = d_in[6];
  const void* Wih  = d_in[7];
  const void* Whh  = d_in[8];
  const void* bih  = d_in[9];
  const void* bhh  = d_in[10];
  const void* Wout = d_in[11];
  const void* bout = d_in[12];

  bf16* Z = (bf16*)d_ws;  // [1024 x 4096] bf16, 8 MB

  k_zgemm<<<dim3(1024), dim3(256), 0, stream>>>(h0, Wsoc, Z, xabs);
  k_fused<<<dim3(256), dim3(256), 0, stream>>>(xabs, h0, Wemb, bemb, bsoc, Wih,
                                               Whh, bih, bhh, c0, Wout, bout, Z,
                                               d_out);
}

// Round 7
// 129.283 us; speedup vs baseline: 2.8627x; 1.1153x over previous
//
#include <hip/hip_runtime.h>
#include <hip/hip_bf16.h>
#include <math.h>

typedef __hip_bfloat16 bf16;
typedef short s8v __attribute__((ext_vector_type(8)));   // 8 bf16 (4 VGPRs)
typedef float f4v __attribute__((ext_vector_type(4)));   // MFMA acc

__device__ __forceinline__ float b2f(bf16 v) { return __bfloat162float(v); }

template <bool F32>
__device__ __forceinline__ float ld(const void* p, int i) {
  if (F32) return ((const float*)p)[i];
  return b2f(((const bf16*)p)[i]);
}

// 8 consecutive elems as a bf16x8 MFMA fragment (f32: 2 float4 + cvt).
template <bool F32>
__device__ __forceinline__ s8v ldfrag(const void* p, size_t i) {
  if (F32) {
    const float* f = (const float*)p + i;
    float4 u = *reinterpret_cast<const float4*>(f);
    float4 v = *reinterpret_cast<const float4*>(f + 4);
    s8v r;
    bf16 t;
    t = __float2bfloat16(u.x); r[0] = *(short*)&t;
    t = __float2bfloat16(u.y); r[1] = *(short*)&t;
    t = __float2bfloat16(u.z); r[2] = *(short*)&t;
    t = __float2bfloat16(u.w); r[3] = *(short*)&t;
    t = __float2bfloat16(v.x); r[4] = *(short*)&t;
    t = __float2bfloat16(v.y); r[5] = *(short*)&t;
    t = __float2bfloat16(v.z); r[6] = *(short*)&t;
    t = __float2bfloat16(v.w); r[7] = *(short*)&t;
    return r;
  }
  return *reinterpret_cast<const s8v*>((const bf16*)p + i);
}

__device__ __forceinline__ float sigm(float x) {
  return 0.5f * (1.0f + tanhf(0.5f * x));
}

// Wave-uniform dtype detect (validated R2-R6).
__device__ __forceinline__ bool detect_f32(const void* xabs) {
  unsigned short v = ((const unsigned short*)xabs)[threadIdx.x & 63];
  int ex = (v >> 7) & 0xFF;
  return __ballot(ex >= 0x93) != 0ull;
}

// ---------------------------------------------------------------------------
// K0: convert weights to bf16 in ws (f32 mode: cvt; bf16 mode: copy).
// Counts divisible by 4. grid 128 x 256.
// ---------------------------------------------------------------------------
template <bool F32>
__device__ __forceinline__ void cvt4(const void* src, bf16* __restrict__ dst,
                                     int count, int gt, int gsz) {
  for (int i = gt * 4; i < count; i += gsz * 4) {
    if (F32) {
      float4 v = *reinterpret_cast<const float4*>((const float*)src + i);
      bf16 t[4] = {__float2bfloat16(v.x), __float2bfloat16(v.y),
                   __float2bfloat16(v.z), __float2bfloat16(v.w)};
      *reinterpret_cast<uint2*>(&dst[i]) = *reinterpret_cast<uint2*>(t);
    } else {
      *reinterpret_cast<uint2*>(&dst[i]) =
          *reinterpret_cast<const uint2*>((const bf16*)src + i);
    }
  }
}

__global__ __launch_bounds__(256) void k_prep(const void* Wsoc, const void* Wih,
                                              const void* Whh, const void* Wout,
                                              bf16* Wsoc_b, bf16* Wih_b,
                                              bf16* Whh_b, bf16* Wout_b,
                                              const void* xabs) {
  const int gt = blockIdx.x * 256 + threadIdx.x;
  const int gsz = gridDim.x * 256;
  if (detect_f32(xabs)) {
    cvt4<true>(Wsoc, Wsoc_b, 64 * 8192, gt, gsz);
    cvt4<true>(Wih, Wih_b, 512 * 128, gt, gsz);
    cvt4<true>(Whh, Whh_b, 512 * 128, gt, gsz);
    cvt4<true>(Wout, Wout_b, 120 * 128, gt, gsz);
  } else {
    cvt4<false>(Wsoc, Wsoc_b, 64 * 8192, gt, gsz);
    cvt4<false>(Wih, Wih_b, 512 * 128, gt, gsz);
    cvt4<false>(Whh, Whh_b, 512 * 128, gt, gsz);
    cvt4<false>(Wout, Wout_b, 120 * 128, gt, gsz);
  }
}

// ---------------------------------------------------------------------------
// K1: Z[m, g*64+e] = sum_d h0[m,d]*Wsoc[e, g*128+d] (bf16). MFMA 16x16x32.
// grid 1024: mt = b&63, wave w -> g = (b>>6)*4 + w. B from pre-cvt Wsoc_b.
// ---------------------------------------------------------------------------
template <bool F32>
__device__ __forceinline__ void zgemm_body(const void* h0,
                                           const bf16* __restrict__ Wsoc_b,
                                           bf16* __restrict__ Z) {
  const int wave = threadIdx.x >> 6, lane = threadIdx.x & 63;
  const int mt = blockIdx.x & 63;
  const int g  = (blockIdx.x >> 6) * 4 + wave;
  const int r16 = lane & 15, quad = lane >> 4;
  s8v afr[4];
#pragma unroll
  for (int kq = 0; kq < 4; ++kq)
    afr[kq] = ldfrag<F32>(h0, (size_t)(mt * 16 + r16) * 128 + kq * 32 + quad * 8);
  f4v acc[4] = {{0.f, 0.f, 0.f, 0.f}, {0.f, 0.f, 0.f, 0.f},
                {0.f, 0.f, 0.f, 0.f}, {0.f, 0.f, 0.f, 0.f}};
#pragma unroll
  for (int t = 0; t < 4; ++t) {
#pragma unroll
    for (int kq = 0; kq < 4; ++kq) {
      s8v bfr = *reinterpret_cast<const s8v*>(
          &Wsoc_b[(size_t)(t * 16 + r16) * 8192 + g * 128 + kq * 32 + quad * 8]);
      acc[t] = __builtin_amdgcn_mfma_f32_16x16x32_bf16(afr[kq], bfr, acc[t],
                                                       0, 0, 0);
    }
  }
#pragma unroll
  for (int t = 0; t < 4; ++t)
#pragma unroll
    for (int reg = 0; reg < 4; ++reg)
      Z[(size_t)(mt * 16 + quad * 4 + reg) * 4096 + g * 64 + t * 16 + r16] =
          __float2bfloat16(acc[t][reg]);
}

__global__ __launch_bounds__(256) void k_zgemm(const void* h0,
                                               const bf16* Wsoc_b,
                                               bf16* __restrict__ Z,
                                               const void* xabs) {
  if (detect_f32(xabs)) zgemm_body<true>(h0, Wsoc_b, Z);
  else                  zgemm_body<false>(h0, Wsoc_b, Z);
}

// ---------------------------------------------------------------------------
// K2 (fused): block = 4 n's. gather -> gates MFMA -> LSTM -> out MFMA.
// LDS: [0,32K) G f32[16][512] (aliases lists[4][1024] in gather phase)
//      Xb bf16[16][264] (padded), Hb bf16[16][136] (padded)
// Weights read as bf16 from ws (pre-converted).
// ---------------------------------------------------------------------------
#define XS 264  // Xb row stride (256 + 8 pad)
#define HS 136  // Hb row stride (128 + 8 pad)

template <bool F32>
__device__ __forceinline__ void fused_body(
    const void* xabs, const void* h0, const void* Wemb, const void* bemb,
    const void* bsoc, const bf16* __restrict__ Wih_b,
    const bf16* __restrict__ Whh_b, const void* bih, const void* bhh,
    const void* c0, const bf16* __restrict__ Wout_b, const void* bout,
    const bf16* __restrict__ Z, void* out, char* smem) {
  float* G   = (float*)smem;           // [16][512] (32 KB)
  int* lists = (int*)smem;             // [4][1024] (gather phase only)
  bf16* Xb   = (bf16*)(smem + 32768);  // [16][XS]
  bf16* Hb   = (bf16*)(smem + 32768 + 16 * XS * 2);  // [16][HS]
  const int tid = threadIdx.x;
  const int wave = tid >> 6, lane = tid & 63;
  const int r16 = lane & 15, quad = lane >> 4;

  // zero pad rows 4..15 (rows 0..3 fully written below)
  for (int idx = 4 * XS + tid; idx < 16 * XS; idx += 256)
    Xb[idx] = __float2bfloat16(0.f);
  for (int idx = 4 * HS + tid; idx < 16 * HS; idx += 256)
    Hb[idx] = __float2bfloat16(0.f);

  // ---- gather ----
  const int n = blockIdx.x * 4 + wave;
  const float xn = ld<F32>(xabs, 2 * n);
  const float yn = ld<F32>(xabs, 2 * n + 1);
  const float tx = xn - 0.2f, ty = yn - 0.2f;
  int* mylist = lists + wave * 1024;
  int cnt = 0;
  for (int c = 0; c < 16; ++c) {
    const int m = c * 64 + lane;
    float dx = ld<F32>(xabs, 2 * m) - tx;
    float dy = ld<F32>(xabs, 2 * m + 1) - ty;
    int cx = (int)floorf(dx / 0.4f * 8.0f);
    int cy = (int)floorf(dy / 0.4f * 8.0f);
    bool valid = (dx >= 0.f) & (dx < 0.4f) & (dy >= 0.f) & (dy < 0.4f) &
                 (cx >= 0) & (cx < 8) & (cy >= 0) & (cy < 8) & (m != n);
    unsigned long long msk = __ballot(valid);
    if (valid) {
      int pos = cnt + __popcll(msk & ((1ull << lane) - 1ull));
      mylist[pos] = (m << 6) | (cx + cy * 8);
    }
    cnt += __popcll(msk);
  }
  float a0 = 0.f, a1 = 0.f, a2 = 0.f, a3 = 0.f;
  float a4 = 0.f, a5 = 0.f, a6 = 0.f, a7 = 0.f;
  int i = 0;
  for (; i + 8 <= cnt; i += 8) {
    int e0 = mylist[i],     e1 = mylist[i + 1];
    int e2 = mylist[i + 2], e3 = mylist[i + 3];
    int e4 = mylist[i + 4], e5 = mylist[i + 5];
    int e6 = mylist[i + 6], e7 = mylist[i + 7];
    a0 += b2f(Z[(size_t)(e0 >> 6) * 4096 + (e0 & 63) * 64 + lane]);
    a1 += b2f(Z[(size_t)(e1 >> 6) * 4096 + (e1 & 63) * 64 + lane]);
    a2 += b2f(Z[(size_t)(e2 >> 6) * 4096 + (e2 & 63) * 64 + lane]);
    a3 += b2f(Z[(size_t)(e3 >> 6) * 4096 + (e3 & 63) * 64 + lane]);
    a4 += b2f(Z[(size_t)(e4 >> 6) * 4096 + (e4 & 63) * 64 + lane]);
    a5 += b2f(Z[(size_t)(e5 >> 6) * 4096 + (e5 & 63) * 64 + lane]);
    a6 += b2f(Z[(size_t)(e6 >> 6) * 4096 + (e6 & 63) * 64 + lane]);
    a7 += b2f(Z[(size_t)(e7 >> 6) * 4096 + (e7 & 63) * 64 + lane]);
  }
  for (; i < cnt; ++i) {
    int e0 = mylist[i];
    a0 += b2f(Z[(size_t)(e0 >> 6) * 4096 + (e0 & 63) * 64 + lane]);
  }
  float pool = ((a0 + a1) + (a2 + a3)) + ((a4 + a5) + (a6 + a7));
  pool = fmaxf(pool + ld<F32>(bsoc, lane), 0.f);
  float emb = fmaxf(ld<F32>(Wemb, lane * 2) * xn +
                        ld<F32>(Wemb, lane * 2 + 1) * yn + ld<F32>(bemb, lane),
                    0.f);
  Xb[wave * XS + lane] = __float2bfloat16(emb);
  Xb[wave * XS + 64 + lane] = __float2bfloat16(pool);
  Xb[wave * XS + 128 + lane] = __float2bfloat16(ld<F32>(h0, n * 128 + lane));
  Xb[wave * XS + 192 + lane] =
      __float2bfloat16(ld<F32>(h0, n * 128 + 64 + lane));
  __syncthreads();  // lists dead; G live from here

  // ---- gates MFMA: G[m, j] = X[m,:] . W_cat[j,:], j = wave*128 + jt*16+r16
  s8v afr[8];
#pragma unroll
  for (int kq = 0; kq < 8; ++kq)
    afr[kq] = *reinterpret_cast<const s8v*>(&Xb[r16 * XS + kq * 32 + quad * 8]);
  const int j0w = wave * 128;
  f4v bacc[8];
#pragma unroll
  for (int jt = 0; jt < 8; ++jt) bacc[jt] = (f4v){0.f, 0.f, 0.f, 0.f};
#pragma unroll
  for (int jt = 0; jt < 8; ++jt) {
    int j = j0w + jt * 16 + r16;
#pragma unroll
    for (int kq = 0; kq < 4; ++kq) {
      s8v bfr = *reinterpret_cast<const s8v*>(
          &Wih_b[(size_t)j * 128 + kq * 32 + quad * 8]);
      bacc[jt] = __builtin_amdgcn_mfma_f32_16x16x32_bf16(afr[kq], bfr, bacc[jt],
                                                         0, 0, 0);
    }
#pragma unroll
    for (int kq = 0; kq < 4; ++kq) {
      s8v bfr = *reinterpret_cast<const s8v*>(
          &Whh_b[(size_t)j * 128 + kq * 32 + quad * 8]);
      bacc[jt] = __builtin_amdgcn_mfma_f32_16x16x32_bf16(afr[kq + 4], bfr,
                                                         bacc[jt], 0, 0, 0);
    }
  }
#pragma unroll
  for (int jt = 0; jt < 8; ++jt) {
    int j = j0w + jt * 16 + r16;
    float bias = ld<F32>(bih, j) + ld<F32>(bhh, j);
#pragma unroll
    for (int reg = 0; reg < 4; ++reg)
      G[(quad * 4 + reg) * 512 + j] = bacc[jt][reg] + bias;
  }
  __syncthreads();

  // ---- LSTM elementwise (rows 0..3 valid) ----
  for (int idx = tid; idx < 512; idx += 256) {
    int m = idx >> 7, tt = idx & 127;
    float ig = G[m * 512 + tt], fg = G[m * 512 + 128 + tt];
    float gg = G[m * 512 + 256 + tt], og = G[m * 512 + 384 + tt];
    float c = sigm(fg) * ld<F32>(c0, (blockIdx.x * 4 + m) * 128 + tt) +
              sigm(ig) * tanhf(gg);
    Hb[m * HS + tt] = __float2bfloat16(sigm(og) * tanhf(c));
  }
  __syncthreads();

  // ---- out MFMA: O[m, j] = H[m,:] . Wout[j,:], j < 120 ----
  s8v hfr[4];
#pragma unroll
  for (int kq = 0; kq < 4; ++kq)
    hfr[kq] = *reinterpret_cast<const s8v*>(&Hb[r16 * HS + kq * 32 + quad * 8]);
#pragma unroll
  for (int jt2 = 0; jt2 < 2; ++jt2) {
    int j = wave * 32 + jt2 * 16 + r16;
    int jj = j < 120 ? j : 119;
    f4v oacc = (f4v){0.f, 0.f, 0.f, 0.f};
#pragma unroll
    for (int kq = 0; kq < 4; ++kq) {
      s8v bfr = *reinterpret_cast<const s8v*>(
          &Wout_b[(size_t)jj * 128 + kq * 32 + quad * 8]);
      oacc = __builtin_amdgcn_mfma_f32_16x16x32_bf16(hfr[kq], bfr, oacc, 0, 0, 0);
    }
    if (j < 120 && quad == 0) {
      float bo = ld<F32>(bout, j);
      int kk = j / 20, mm = j % 20;
#pragma unroll
      for (int reg = 0; reg < 4; ++reg) {
        int oi = kk * 20480 + (blockIdx.x * 4 + reg) * 20 + mm;
        float val = oacc[reg] + bo;
        if (F32) ((float*)out)[oi] = val;
        else     ((bf16*)out)[oi] = __float2bfloat16(val);
      }
    }
  }
}

__global__ __launch_bounds__(256, 1) void k_fused(
    const void* xabs, const void* h0, const void* Wemb, const void* bemb,
    const void* bsoc, const bf16* Wih_b, const bf16* Whh_b, const void* bih,
    const void* bhh, const void* c0, const bf16* Wout_b, const void* bout,
    const bf16* __restrict__ Z, void* out) {
  __shared__ __align__(16) char smem[32768 + 16 * XS * 2 + 16 * HS * 2];
  if (detect_f32(xabs))
    fused_body<true>(xabs, h0, Wemb, bemb, bsoc, Wih_b, Whh_b, bih, bhh, c0,
                     Wout_b, bout, Z, out, smem);
  else
    fused_body<false>(xabs, h0, Wemb, bemb, bsoc, Wih_b, Whh_b, bih, bhh, c0,
                      Wout_b, bout, Z, out, smem);
}

// ---------------------------------------------------------------------------
extern "C" void kernel_launch(void* const* d_in, const int* in_sizes, int n_in,
                              void* d_out, int out_size, void* d_ws, size_t ws_size,
                              hipStream_t stream) {
  const void* xabs = d_in[0];
  const void* h0   = d_in[1];
  const void* c0   = d_in[2];
  const void* Wemb = d_in[3];
  const void* bemb = d_in[4];
  const void* Wsoc = d_in[5];
  const void* bsoc = d_in[6];
  const void* Wih  = d_in[7];
  const void* Whh  = d_in[8];
  const void* bih  = d_in[9];
  const void* bhh  = d_in[10];
  const void* Wout = d_in[11];
  const void* bout = d_in[12];

  // ws: Z bf16[1024*4096] | Wsoc_b 1MB | Wih_b 256KB... (all bf16)
  bf16* Z      = (bf16*)d_ws;
  bf16* Wsoc_b = Z + (size_t)1024 * 4096;
  bf16* Wih_b  = Wsoc_b + (size_t)64 * 8192;
  bf16* Whh_b  = Wih_b + (size_t)512 * 128;
  bf16* Wout_b = Whh_b + (size_t)512 * 128;

  k_prep<<<dim3(128), dim3(256), 0, stream>>>(Wsoc, Wih, Whh, Wout, Wsoc_b,
                                              Wih_b, Whh_b, Wout_b, xabs);
  k_zgemm<<<dim3(1024), dim3(256), 0, stream>>>(h0, Wsoc_b, Z, xabs);
  k_fused<<<dim3(256), dim3(256), 0, stream>>>(xabs, h0, Wemb, bemb, bsoc,
                                               Wih_b, Whh_b, bih, bhh, c0,
                                               Wout_b, bout, Z, d_out);
}

// Round 8
// 123.447 us; speedup vs baseline: 2.9981x; 1.0473x over previous
//
#include <hip/hip_runtime.h>
#include <hip/hip_bf16.h>
#include <math.h>

typedef __hip_bfloat16 bf16;
typedef short s8v __attribute__((ext_vector_type(8)));   // 8 bf16 (4 VGPRs)
typedef float f4v __attribute__((ext_vector_type(4)));   // MFMA acc

__device__ __forceinline__ float b2f(bf16 v) { return __bfloat162float(v); }

template <bool F32>
__device__ __forceinline__ float ld(const void* p, int i) {
  if (F32) return ((const float*)p)[i];
  return b2f(((const bf16*)p)[i]);
}

// 8 consecutive elems as a bf16x8 MFMA fragment (f32: 2 float4 + cvt).
template <bool F32>
__device__ __forceinline__ s8v ldfrag(const void* p, size_t i) {
  if (F32) {
    const float* f = (const float*)p + i;
    float4 u = *reinterpret_cast<const float4*>(f);
    float4 v = *reinterpret_cast<const float4*>(f + 4);
    s8v r;
    bf16 t;
    t = __float2bfloat16(u.x); r[0] = *(short*)&t;
    t = __float2bfloat16(u.y); r[1] = *(short*)&t;
    t = __float2bfloat16(u.z); r[2] = *(short*)&t;
    t = __float2bfloat16(u.w); r[3] = *(short*)&t;
    t = __float2bfloat16(v.x); r[4] = *(short*)&t;
    t = __float2bfloat16(v.y); r[5] = *(short*)&t;
    t = __float2bfloat16(v.z); r[6] = *(short*)&t;
    t = __float2bfloat16(v.w); r[7] = *(short*)&t;
    return r;
  }
  return *reinterpret_cast<const s8v*>((const bf16*)p + i);
}

__device__ __forceinline__ float sigm(float x) {
  return 0.5f * (1.0f + tanhf(0.5f * x));
}

// Wave-uniform dtype detect (validated R2-R7).
__device__ __forceinline__ bool detect_f32(const void* xabs) {
  unsigned short v = ((const unsigned short*)xabs)[threadIdx.x & 63];
  int ex = (v >> 7) & 0xFF;
  return __ballot(ex >= 0x93) != 0ull;
}

// ---------------------------------------------------------------------------
// K1: blocks 0..255: Z = h0 @ Wsoc^T tiles (64m x 256e per block, MFMA,
// direct reads with in-register cvt). blocks 256..271: cvt Wih/Whh/Wout
// to bf16 in ws for k_fused.
// ---------------------------------------------------------------------------
template <bool F32>
__device__ __forceinline__ void cvt4(const void* src, bf16* __restrict__ dst,
                                     int count, int gt, int gsz) {
  for (int i = gt * 4; i < count; i += gsz * 4) {
    if (F32) {
      float4 v = *reinterpret_cast<const float4*>((const float*)src + i);
      bf16 t[4] = {__float2bfloat16(v.x), __float2bfloat16(v.y),
                   __float2bfloat16(v.z), __float2bfloat16(v.w)};
      *reinterpret_cast<uint2*>(&dst[i]) = *reinterpret_cast<uint2*>(t);
    } else {
      *reinterpret_cast<uint2*>(&dst[i]) =
          *reinterpret_cast<const uint2*>((const bf16*)src + i);
    }
  }
}

template <bool F32>
__device__ __forceinline__ void zgemm_body(const void* h0, const void* Wsoc,
                                           const void* Wih, const void* Whh,
                                           const void* Wout,
                                           bf16* __restrict__ Z, bf16* Wih_b,
                                           bf16* Whh_b, bf16* Wout_b) {
  if (blockIdx.x >= 256) {  // weight-cvt blocks
    const int gt = (blockIdx.x - 256) * 256 + threadIdx.x;
    const int gsz = 16 * 256;
    cvt4<F32>(Wih, Wih_b, 512 * 128, gt, gsz);
    cvt4<F32>(Whh, Whh_b, 512 * 128, gt, gsz);
    cvt4<F32>(Wout, Wout_b, 120 * 128, gt, gsz);
    return;
  }
  const int wave = threadIdx.x >> 6, lane = threadIdx.x & 63;
  const int mt = blockIdx.x & 15;        // 16 m-tiles of 64 rows
  const int g  = (blockIdx.x >> 4) * 4 + wave;  // 64 g's
  const int r16 = lane & 15, quad = lane >> 4;

  s8v afr[4][4];  // [ms][kq]
#pragma unroll
  for (int ms = 0; ms < 4; ++ms)
#pragma unroll
    for (int kq = 0; kq < 4; ++kq)
      afr[ms][kq] = ldfrag<F32>(
          h0, (size_t)(mt * 64 + ms * 16 + r16) * 128 + kq * 32 + quad * 8);

  f4v acc[4][4];  // [ms][t]
#pragma unroll
  for (int ms = 0; ms < 4; ++ms)
#pragma unroll
    for (int t = 0; t < 4; ++t) acc[ms][t] = (f4v){0.f, 0.f, 0.f, 0.f};

#pragma unroll
  for (int t = 0; t < 4; ++t) {
#pragma unroll
    for (int kq = 0; kq < 4; ++kq) {
      s8v bfr = ldfrag<F32>(
          Wsoc, (size_t)(t * 16 + r16) * 8192 + g * 128 + kq * 32 + quad * 8);
#pragma unroll
      for (int ms = 0; ms < 4; ++ms)
        acc[ms][t] = __builtin_amdgcn_mfma_f32_16x16x32_bf16(afr[ms][kq], bfr,
                                                             acc[ms][t], 0, 0, 0);
    }
  }
#pragma unroll
  for (int ms = 0; ms < 4; ++ms)
#pragma unroll
    for (int t = 0; t < 4; ++t)
#pragma unroll
      for (int reg = 0; reg < 4; ++reg)
        Z[(size_t)(mt * 64 + ms * 16 + quad * 4 + reg) * 4096 + g * 64 +
          t * 16 + r16] = __float2bfloat16(acc[ms][t][reg]);
}

__global__ __launch_bounds__(256, 1) void k_zgemm(
    const void* h0, const void* Wsoc, const void* Wih, const void* Whh,
    const void* Wout, bf16* __restrict__ Z, bf16* Wih_b, bf16* Whh_b,
    bf16* Wout_b, const void* xabs) {
  if (detect_f32(xabs))
    zgemm_body<true>(h0, Wsoc, Wih, Whh, Wout, Z, Wih_b, Whh_b, Wout_b);
  else
    zgemm_body<false>(h0, Wsoc, Wih, Whh, Wout, Z, Wih_b, Whh_b, Wout_b);
}

// ---------------------------------------------------------------------------
// K2 (fused): block = 4 n's. gather -> gates MFMA -> LSTM -> out MFMA.
// LDS: [0,32K) G f32[16][512] (aliases lists[4][1024] in gather phase)
//      Xb bf16[16][264] (padded), Hb bf16[16][136] (padded)
// ---------------------------------------------------------------------------
#define XS 264
#define HS 136

template <bool F32>
__device__ __forceinline__ void fused_body(
    const void* xabs, const void* h0, const void* Wemb, const void* bemb,
    const void* bsoc, const bf16* __restrict__ Wih_b,
    const bf16* __restrict__ Whh_b, const void* bih, const void* bhh,
    const void* c0, const bf16* __restrict__ Wout_b, const void* bout,
    const bf16* __restrict__ Z, void* out, char* smem) {
  float* G   = (float*)smem;           // [16][512]
  int* lists = (int*)smem;             // [4][1024] (gather phase only)
  bf16* Xb   = (bf16*)(smem + 32768);  // [16][XS]
  bf16* Hb   = (bf16*)(smem + 32768 + 16 * XS * 2);  // [16][HS]
  const int tid = threadIdx.x;
  const int wave = tid >> 6, lane = tid & 63;
  const int r16 = lane & 15, quad = lane >> 4;

  for (int idx = 4 * XS + tid; idx < 16 * XS; idx += 256)
    Xb[idx] = __float2bfloat16(0.f);
  for (int idx = 4 * HS + tid; idx < 16 * HS; idx += 256)
    Hb[idx] = __float2bfloat16(0.f);

  // ---- gather ----
  const int n = blockIdx.x * 4 + wave;
  const float xn = ld<F32>(xabs, 2 * n);
  const float yn = ld<F32>(xabs, 2 * n + 1);
  const float tx = xn - 0.2f, ty = yn - 0.2f;
  int* mylist = lists + wave * 1024;
  int cnt = 0;
  for (int c = 0; c < 16; ++c) {
    const int m = c * 64 + lane;
    float dx = ld<F32>(xabs, 2 * m) - tx;
    float dy = ld<F32>(xabs, 2 * m + 1) - ty;
    int cx = (int)floorf(dx / 0.4f * 8.0f);
    int cy = (int)floorf(dy / 0.4f * 8.0f);
    bool valid = (dx >= 0.f) & (dx < 0.4f) & (dy >= 0.f) & (dy < 0.4f) &
                 (cx >= 0) & (cx < 8) & (cy >= 0) & (cy < 8) & (m != n);
    unsigned long long msk = __ballot(valid);
    if (valid) {
      int pos = cnt + __popcll(msk & ((1ull << lane) - 1ull));
      mylist[pos] = (m << 6) | (cx + cy * 8);
    }
    cnt += __popcll(msk);
  }
  float a0 = 0.f, a1 = 0.f, a2 = 0.f, a3 = 0.f;
  float a4 = 0.f, a5 = 0.f, a6 = 0.f, a7 = 0.f;
  int i = 0;
  for (; i + 8 <= cnt; i += 8) {
    int e0 = mylist[i],     e1 = mylist[i + 1];
    int e2 = mylist[i + 2], e3 = mylist[i + 3];
    int e4 = mylist[i + 4], e5 = mylist[i + 5];
    int e6 = mylist[i + 6], e7 = mylist[i + 7];
    a0 += b2f(Z[(size_t)(e0 >> 6) * 4096 + (e0 & 63) * 64 + lane]);
    a1 += b2f(Z[(size_t)(e1 >> 6) * 4096 + (e1 & 63) * 64 + lane]);
    a2 += b2f(Z[(size_t)(e2 >> 6) * 4096 + (e2 & 63) * 64 + lane]);
    a3 += b2f(Z[(size_t)(e3 >> 6) * 4096 + (e3 & 63) * 64 + lane]);
    a4 += b2f(Z[(size_t)(e4 >> 6) * 4096 + (e4 & 63) * 64 + lane]);
    a5 += b2f(Z[(size_t)(e5 >> 6) * 4096 + (e5 & 63) * 64 + lane]);
    a6 += b2f(Z[(size_t)(e6 >> 6) * 4096 + (e6 & 63) * 64 + lane]);
    a7 += b2f(Z[(size_t)(e7 >> 6) * 4096 + (e7 & 63) * 64 + lane]);
  }
  for (; i < cnt; ++i) {
    int e0 = mylist[i];
    a0 += b2f(Z[(size_t)(e0 >> 6) * 4096 + (e0 & 63) * 64 + lane]);
  }
  float pool = ((a0 + a1) + (a2 + a3)) + ((a4 + a5) + (a6 + a7));
  pool = fmaxf(pool + ld<F32>(bsoc, lane), 0.f);
  float emb = fmaxf(ld<F32>(Wemb, lane * 2) * xn +
                        ld<F32>(Wemb, lane * 2 + 1) * yn + ld<F32>(bemb, lane),
                    0.f);
  Xb[wave * XS + lane] = __float2bfloat16(emb);
  Xb[wave * XS + 64 + lane] = __float2bfloat16(pool);
  Xb[wave * XS + 128 + lane] = __float2bfloat16(ld<F32>(h0, n * 128 + lane));
  Xb[wave * XS + 192 + lane] =
      __float2bfloat16(ld<F32>(h0, n * 128 + 64 + lane));
  __syncthreads();  // lists dead; G live from here

  // ---- gates MFMA ----
  s8v afr[8];
#pragma unroll
  for (int kq = 0; kq < 8; ++kq)
    afr[kq] = *reinterpret_cast<const s8v*>(&Xb[r16 * XS + kq * 32 + quad * 8]);
  const int j0w = wave * 128;
  f4v bacc[8];
#pragma unroll
  for (int jt = 0; jt < 8; ++jt) bacc[jt] = (f4v){0.f, 0.f, 0.f, 0.f};
#pragma unroll
  for (int jt = 0; jt < 8; ++jt) {
    int j = j0w + jt * 16 + r16;
#pragma unroll
    for (int kq = 0; kq < 4; ++kq) {
      s8v bfr = *reinterpret_cast<const s8v*>(
          &Wih_b[(size_t)j * 128 + kq * 32 + quad * 8]);
      bacc[jt] = __builtin_amdgcn_mfma_f32_16x16x32_bf16(afr[kq], bfr, bacc[jt],
                                                         0, 0, 0);
    }
#pragma unroll
    for (int kq = 0; kq < 4; ++kq) {
      s8v bfr = *reinterpret_cast<const s8v*>(
          &Whh_b[(size_t)j * 128 + kq * 32 + quad * 8]);
      bacc[jt] = __builtin_amdgcn_mfma_f32_16x16x32_bf16(afr[kq + 4], bfr,
                                                         bacc[jt], 0, 0, 0);
    }
  }
#pragma unroll
  for (int jt = 0; jt < 8; ++jt) {
    int j = j0w + jt * 16 + r16;
    float bias = ld<F32>(bih, j) + ld<F32>(bhh, j);
#pragma unroll
    for (int reg = 0; reg < 4; ++reg)
      G[(quad * 4 + reg) * 512 + j] = bacc[jt][reg] + bias;
  }
  __syncthreads();

  // ---- LSTM elementwise ----
  for (int idx = tid; idx < 512; idx += 256) {
    int m = idx >> 7, tt = idx & 127;
    float ig = G[m * 512 + tt], fg = G[m * 512 + 128 + tt];
    float gg = G[m * 512 + 256 + tt], og = G[m * 512 + 384 + tt];
    float c = sigm(fg) * ld<F32>(c0, (blockIdx.x * 4 + m) * 128 + tt) +
              sigm(ig) * tanhf(gg);
    Hb[m * HS + tt] = __float2bfloat16(sigm(og) * tanhf(c));
  }
  __syncthreads();

  // ---- out MFMA ----
  s8v hfr[4];
#pragma unroll
  for (int kq = 0; kq < 4; ++kq)
    hfr[kq] = *reinterpret_cast<const s8v*>(&Hb[r16 * HS + kq * 32 + quad * 8]);
#pragma unroll
  for (int jt2 = 0; jt2 < 2; ++jt2) {
    int j = wave * 32 + jt2 * 16 + r16;
    int jj = j < 120 ? j : 119;
    f4v oacc = (f4v){0.f, 0.f, 0.f, 0.f};
#pragma unroll
    for (int kq = 0; kq < 4; ++kq) {
      s8v bfr = *reinterpret_cast<const s8v*>(
          &Wout_b[(size_t)jj * 128 + kq * 32 + quad * 8]);
      oacc = __builtin_amdgcn_mfma_f32_16x16x32_bf16(hfr[kq], bfr, oacc, 0, 0, 0);
    }
    if (j < 120 && quad == 0) {
      float bo = ld<F32>(bout, j);
      int kk = j / 20, mm = j % 20;
#pragma unroll
      for (int reg = 0; reg < 4; ++reg) {
        int oi = kk * 20480 + (blockIdx.x * 4 + reg) * 20 + mm;
        float val = oacc[reg] + bo;
        if (F32) ((float*)out)[oi] = val;
        else     ((bf16*)out)[oi] = __float2bfloat16(val);
      }
    }
  }
}

__global__ __launch_bounds__(256, 1) void k_fused(
    const void* xabs, const void* h0, const void* Wemb, const void* bemb,
    const void* bsoc, const bf16* Wih_b, const bf16* Whh_b, const void* bih,
    const void* bhh, const void* c0, const bf16* Wout_b, const void* bout,
    const bf16* __restrict__ Z, void* out) {
  __shared__ __align__(16) char smem[32768 + 16 * XS * 2 + 16 * HS * 2];
  if (detect_f32(xabs))
    fused_body<true>(xabs, h0, Wemb, bemb, bsoc, Wih_b, Whh_b, bih, bhh, c0,
                     Wout_b, bout, Z, out, smem);
  else
    fused_body<false>(xabs, h0, Wemb, bemb, bsoc, Wih_b, Whh_b, bih, bhh, c0,
                      Wout_b, bout, Z, out, smem);
}

// ---------------------------------------------------------------------------
extern "C" void kernel_launch(void* const* d_in, const int* in_sizes, int n_in,
                              void* d_out, int out_size, void* d_ws, size_t ws_size,
                              hipStream_t stream) {
  const void* xabs = d_in[0];
  const void* h0   = d_in[1];
  const void* c0   = d_in[2];
  const void* Wemb = d_in[3];
  const void* bemb = d_in[4];
  const void* Wsoc = d_in[5];
  const void* bsoc = d_in[6];
  const void* Wih  = d_in[7];
  const void* Whh  = d_in[8];
  const void* bih  = d_in[9];
  const void* bhh  = d_in[10];
  const void* Wout = d_in[11];
  const void* bout = d_in[12];

  // ws: Z bf16[1024*4096] | Wih_b | Whh_b | Wout_b
  bf16* Z      = (bf16*)d_ws;
  bf16* Wih_b  = Z + (size_t)1024 * 4096;
  bf16* Whh_b  = Wih_b + (size_t)512 * 128;
  bf16* Wout_b = Whh_b + (size_t)512 * 128;

  k_zgemm<<<dim3(272), dim3(256), 0, stream>>>(h0, Wsoc, Wih, Whh, Wout, Z,
                                               Wih_b, Whh_b, Wout_b, xabs);
  k_fused<<<dim3(256), dim3(256), 0, stream>>>(xabs, h0, Wemb, bemb, bsoc,
                                               Wih_b, Whh_b, bih, bhh, c0,
                                               Wout_b, bout, Z, d_out);
}